// Round 10
// baseline (17.587 us; speedup 1.0000x reference)
//
#include <hip/hip_runtime.h>
#include <math.h>

#define KK 16
#define DD 16
#define NCAT 136
#define NCATP 144           // padded: 16 waves x 9 cats
#define NROWS 20480
#define NBLK 320            // 320 blocks x 1024 thr; Phase-B redundancy unchanged
#define NW 16               // waves per block
#define CPW 9               // categories per wave
#define GS 17               // padded LDS stride for g (odd -> conflict-free)
#define EPSF 1e-6f
#define LOG2PI_F 1.8378770664093453f
#define LN2_F 0.6931471805599453f
#define INV_SQRT2 0.70710678118654752f

// Branch-free erf, Abramowitz-Stegun 7.1.26 (max abs err ~1.5e-7).
__device__ __forceinline__ float erf_fast(float x) {
    float s  = copysignf(1.0f, x);
    float ax = fabsf(x);
    float t  = __builtin_amdgcn_rcpf(fmaf(0.3275911f, ax, 1.0f));
    float y  = t * fmaf(t, fmaf(t, fmaf(t, fmaf(t, 1.061405429f, -1.453152027f),
                                        1.421413741f), -0.284496736f), 0.254829592f);
    return s * (1.0f - y * __expf(-ax * ax));
}

// Closed-form triu(a,b) from flat index c (0..135), K=16:
// start(a) = a*(33-a)/2;  a = floor((33 - sqrt(1089-8c))/2), with +/-1 fixup.
__device__ __forceinline__ void triu_decode(int c, int& a, int& b) {
    float disc = (float)(1089 - 8 * c);
    int aa = (int)((33.0f - sqrtf(disc)) * 0.5f);
    int st = (aa * (33 - aa)) >> 1;
    if (c < st)                        { --aa; st = (aa * (33 - aa)) >> 1; }
    else { int sn = ((aa + 1) * (32 - aa)) >> 1;
           if (c >= sn)                { ++aa; st = sn; } }
    a = aa;
    b = aa + (c - st);
}

// ---------------------------------------------------------------------------
// Main kernel: 320 blocks x 1024 thr = 16 waves, block owns 64 rows
// (row = lane). Wave w handles cats [9w, 9w+9) (c>=136 are pads). Phase A is
// fully uniform: thread (lane=row, wv=col) computes zz and one g' column
// (g' = g - zz/2). Per-cat constants as in R9 (float4: C, ky, kz, K1).
// Pads: ky=0, kz=1e30 (cd=0.5), K1=-1e30 (exp -> 0, exact).
// ---------------------------------------------------------------------------
__global__ __launch_bounds__(1024) void latent_main(
    const float* __restrict__ z,
    const float* __restrict__ pi,
    const float* __restrict__ mu,
    float* __restrict__ partials)
{
    __shared__ float  g_s[64 * GS];
    __shared__ float4 sC4[NCATP];
    __shared__ float  comb_m[NW * 64];
    __shared__ float  comb_s[NW * 64];

    const int t    = threadIdx.x;
    const int wv   = t >> 6;
    const int lane = t & 63;
    const int row  = blockIdx.x * 64 + lane;

    // --- Phase A: z row (L1 absorbs 16x wave reuse), zz, one g' column ---
    const float* zr = z + row * DD;
    float zv[DD];
    #pragma unroll
    for (int i = 0; i < 4; ++i) {
        float4 v = reinterpret_cast<const float4*>(zr)[i];
        zv[4*i+0] = v.x; zv[4*i+1] = v.y; zv[4*i+2] = v.z; zv[4*i+3] = v.w;
    }
    {
        float g0 = 0.f, zz = 0.f;
        #pragma unroll
        for (int d = 0; d < DD; ++d) {
            g0 = fmaf(zv[d], mu[d * KK + wv], g0);
            zz = fmaf(zv[d], zv[d], zz);
        }
        g_s[lane * GS + wv] = fmaf(-0.5f, zz, g0);
    }

    // --- Phase B: per-category constants on waves 0..2 (wave-uniform guard;
    //     all 64 lanes of each wave participate in the shuffles) ---
    if (wv < 3) {
        float pv[3];
        float lmax = -1e30f;
        #pragma unroll
        for (int j = 0; j < 3; ++j) {
            int cc = lane + j * 64;
            pv[j] = (cc < NCAT) ? pi[cc] : -1e30f;
            lmax = fmaxf(lmax, pv[j]);
        }
        #pragma unroll
        for (int off = 32; off > 0; off >>= 1)
            lmax = fmaxf(lmax, __shfl_xor(lmax, off, 64));
        float lsum = 0.f;
        #pragma unroll
        for (int j = 0; j < 3; ++j) {
            int cc = lane + j * 64;
            if (cc < NCAT) lsum += __expf(pv[j] - lmax);
        }
        #pragma unroll
        for (int off = 32; off > 0; off >>= 1)
            lsum += __shfl_xor(lsum, off, 64);

        if (t < NCATP) {
            const int c = t;
            if (c < NCAT) {
                int a, b;
                triu_decode(c, a, b);

                float inv = 0.f, Cc = 0.f, mb2 = 0.f;
                #pragma unroll
                for (int d = 0; d < DD; ++d) {
                    float mb = mu[d * KK + b];
                    float ma = mu[d * KK + a];
                    float al = mb - ma;
                    inv = fmaf(al, al, inv);
                    Cc  = fmaf(al, mb, Cc);
                    mb2 = fmaf(mb, mb, mb2);
                }
                float clipped = fminf(fmaxf(inv, 1e-12f), 1e30f);
                float sq      = sqrtf(clipped);

                float p = __expf(pi[c] - lmax) / lsum;
                p = fminf(fmaxf(p, EPSF), 1.0f);
                float logpi = __logf(p);

                float ky, kz, K1;
                if (a == b) {
                    ky = 0.f;                       // e2 = 0
                    kz = 1e30f;                     // erf(e1)=1 -> cd = 0.5
                    K1 = logpi - 8.f * LOG2PI_F + LN2_F - 0.5f * mb2;
                } else {
                    ky = (1.f / inv) * sq * INV_SQRT2;
                    kz = sq * INV_SQRT2;
                    K1 = logpi - 7.5f * LOG2PI_F - 0.5f * __logf(clipped)
                         - 0.5f * mb2;
                }
                sC4[c] = make_float4(Cc, ky, kz, K1);
            } else {
                sC4[c] = make_float4(0.f, 0.f, 1e30f, -1e30f);  // pad: exp->0
            }
        }
    }
    __syncthreads();   // g_s, sC4 ready

    // --- Phase C: wave w, cats [9w, 9w+9), row = lane ---
    {
        const int c0 = wv * CPW;      // 0..135 (head is always a real cat)
        int a, b;
        triu_decode(c0, a, b);

        const float* grow = &g_s[lane * GS];
        float u[CPW], cdv[CPW];
        float m = -1e30f;
        #pragma unroll
        for (int i = 0; i < CPW; ++i) {
            float4 k  = sC4[c0 + i];             // wave-uniform broadcast
            float ga  = grow[a];
            float gb  = grow[b];
            float sab = gb - ga - k.x;
            float e2  = sab * k.y;
            float e1  = e2 + k.z;
            float uu  = fmaf(e2, e2, k.w + gb);
            float cd  = 0.5f * (erf_fast(e1) - erf_fast(e2));
            cdv[i] = fmaxf(cd, EPSF);
            u[i]   = uu;
            m = fmaxf(m, uu);
            // advance; clamp keeps pad iterations reading valid LDS
            if (++b >= KK) { ++a; b = a; }
            a = (a > 15) ? 15 : a;
            b = (b > 15) ? 15 : b;
        }
        float ssum = 0.f;
        #pragma unroll
        for (int i = 0; i < CPW; ++i)
            ssum = fmaf(__expf(u[i] - m), cdv[i], ssum);
        comb_m[wv * 64 + lane] = m;
        comb_s[wv * 64 + lane] = ssum;
    }
    __syncthreads();

    // --- wave 0: merge 16 wave-partials per row, block-sum, store partial ---
    if (wv == 0) {
        float M = comb_m[lane], S = comb_s[lane];
        #pragma unroll
        for (int ww = 1; ww < NW; ++ww) {
            float mm = comb_m[ww * 64 + lane];
            float ss = comb_s[ww * 64 + lane];
            float nm = fmaxf(M, mm);
            S = S * __expf(M - nm) + ss * __expf(mm - nm);
            M = nm;
        }
        float lp = M + __logf(S);
        #pragma unroll
        for (int off = 32; off > 0; off >>= 1)
            lp += __shfl_xor(lp, off, 64);
        if (lane == 0) partials[blockIdx.x] = lp;
    }
}

// ---------------------------------------------------------------------------
// Final reduction: sum 320 block partials (double, fixed order), /NROWS.
// ---------------------------------------------------------------------------
__global__ __launch_bounds__(64) void latent_reduce(
    const float* __restrict__ partials, float* __restrict__ out)
{
    const int tid = threadIdx.x;
    double s = 0.0;
    #pragma unroll
    for (int j = 0; j < NBLK / 64; ++j)
        s += (double)partials[tid * (NBLK / 64) + j];   // fixed order
    #pragma unroll
    for (int off = 32; off > 0; off >>= 1)
        s += __shfl_xor(s, off, 64);
    if (tid == 0) out[0] = (float)(s / (double)NROWS);
}

extern "C" void kernel_launch(void* const* d_in, const int* in_sizes, int n_in,
                              void* d_out, int out_size, void* d_ws, size_t ws_size,
                              hipStream_t stream) {
    const float* z  = (const float*)d_in[0];   // (2048,10,16) f32
    const float* pi = (const float*)d_in[1];   // (1,136) f32
    const float* mu = (const float*)d_in[2];   // (16,16) f32
    float* out      = (float*)d_out;           // scalar f32
    float* partials = (float*)d_ws;            // 320 floats

    latent_main<<<NBLK, 1024, 0, stream>>>(z, pi, mu, partials);
    latent_reduce<<<1, 64, 0, stream>>>(partials, out);
}